// Round 4
// baseline (27721.136 us; speedup 1.0000x reference)
//
#include <hip/hip_runtime.h>
#include <math.h>

#define BATCH 32
#define TLEN  512
#define HID   1024
#define G2    2048   // 2*H

// ---------------------------------------------------------------------------
// Projection GEMM: Cw[t][b][n] = sum_k A[m][k] * W[n][k],  m = b*TLEN + t
// A: [M,K] row-major (M = 16384), W: [N,K] row-major (N = 2048)
// Output permuted to [T][B][2H] so the recurrence reads contiguous slabs.
// ---------------------------------------------------------------------------
__global__ __launch_bounds__(256)
void proj_gemm(const float* __restrict__ A, const float* __restrict__ W,
               float* __restrict__ Cw, int K) {
    __shared__ float As[16][132];
    __shared__ float Bs[16][132];

    const int bm = blockIdx.x;          // M/128 tiles
    const int bn = blockIdx.y;          // N/128 tiles
    const int tid = threadIdx.x;
    const int tx = tid & 15;            // n micro
    const int ty = tid >> 4;            // m micro

    const int row0 = bm * 128;
    const int col0 = bn * 128;

    float acc[8][8];
    #pragma unroll
    for (int i = 0; i < 8; ++i)
        #pragma unroll
        for (int j = 0; j < 8; ++j) acc[i][j] = 0.f;

    for (int k0 = 0; k0 < K; k0 += 16) {
        #pragma unroll
        for (int i = 0; i < 2; ++i) {
            int f = tid + i * 256;            // float4 id 0..511
            int r = f >> 2;                   // row 0..127
            int c = (f & 3) * 4;              // k 0..12
            float4 va = *(const float4*)&A[(size_t)(row0 + r) * K + k0 + c];
            As[c + 0][r] = va.x; As[c + 1][r] = va.y;
            As[c + 2][r] = va.z; As[c + 3][r] = va.w;
            float4 vb = *(const float4*)&W[(size_t)(col0 + r) * K + k0 + c];
            Bs[c + 0][r] = vb.x; Bs[c + 1][r] = vb.y;
            Bs[c + 2][r] = vb.z; Bs[c + 3][r] = vb.w;
        }
        __syncthreads();

        #pragma unroll
        for (int kk = 0; kk < 16; ++kk) {
            float a[8], b[8];
            #pragma unroll
            for (int i = 0; i < 8; ++i) a[i] = As[kk][ty * 8 + i];
            #pragma unroll
            for (int j = 0; j < 8; ++j) b[j] = Bs[kk][tx * 8 + j];
            #pragma unroll
            for (int i = 0; i < 8; ++i)
                #pragma unroll
                for (int j = 0; j < 8; ++j)
                    acc[i][j] += a[i] * b[j];
        }
        __syncthreads();
    }

    #pragma unroll
    for (int i = 0; i < 8; ++i) {
        int m = row0 + ty * 8 + i;
        int t = m & (TLEN - 1);
        int bb = m >> 9;
        float* dst = &Cw[((size_t)t * BATCH + bb) * G2 + col0 + tx * 8];
        #pragma unroll
        for (int j = 0; j < 8; ++j) dst[j] = acc[i][j];
    }
}

// ---------------------------------------------------------------------------
// Agent-scope (device-coherent) access helpers. Relaxed atomics compile to
// global_load/store with sc0 sc1 (bypass L1 + per-XCD L2, hit LLC) -- no
// cache-maintenance ops, no fences.
// ---------------------------------------------------------------------------
__device__ __forceinline__ void st_flag(int* p, int v) {
    __hip_atomic_store(p, v, __ATOMIC_RELAXED, __HIP_MEMORY_SCOPE_AGENT);
}
__device__ __forceinline__ int ld_flag(const int* p) {
    return __hip_atomic_load(p, __ATOMIC_RELAXED, __HIP_MEMORY_SCOPE_AGENT);
}
__device__ __forceinline__ void st_h(float* p, float v) {
    __hip_atomic_store(p, v, __ATOMIC_RELAXED, __HIP_MEMORY_SCOPE_AGENT);
}
__device__ __forceinline__ float ld_h(const float* p) {
    return __hip_atomic_load(p, __ATOMIC_RELAXED, __HIP_MEMORY_SCOPE_AGENT);
}
__device__ __forceinline__ uint64_t ld_h2(const float* p) {   // 8B coherent load
    return __hip_atomic_load((const uint64_t*)p, __ATOMIC_RELAXED,
                             __HIP_MEMORY_SCOPE_AGENT);
}
__device__ __forceinline__ float lo_f(uint64_t u) {
    return __uint_as_float((uint32_t)u);
}
__device__ __forceinline__ float hi_f(uint64_t u) {
    return __uint_as_float((uint32_t)(u >> 32));
}

#define NWG 256
#define JPW 4
#define FSTRIDE 16   // flags spread 64 B apart

__global__ void rec_init(float* h0, int* flags) {
    int i = blockIdx.x * 256 + threadIdx.x;
    if (i < BATCH * HID) h0[i] = 0.f;
    if (i < NWG * FSTRIDE + 16) flags[i] = 0;   // flags + go word
}

// ---------------------------------------------------------------------------
// Recurrence: persistent kernel. 256 WGs x 512 threads; WG wg owns j in
// [wg*4, wg*4+4), its 8 U rows live in LDS for all 512 steps.
// Thread layout: p = tid&127 -> (b = p>>2, jl = p&3); q = tid>>7 = K-quarter.
// h ping-pongs in global, accessed ONLY via agent-coherent atomics.
//
// Grid barrier: two-hop tree, ONE spinner per WG.
//   arrival : leader of WG 1..255 stores epoch to its own 64B-spread flag.
//   gather  : WG 0 threads 1..255 poll one flag each (only multi-thread
//             polling in the grid), then tid 0 publishes `go` = epoch.
//   release : 255 leaders spin on the single read-only `go` line, s_sleep(4).
// Store->flag ordering: __syncthreads() drains each wave's vmcnt before
// s_barrier, so all h stores are at LLC before the flag store issues.
// ---------------------------------------------------------------------------
__global__ __launch_bounds__(512, 1)
void ligru_rec(const float* __restrict__ w,    // [T][B][2H]
               const float* __restrict__ U,    // [2H][H]
               float* h0w, float* h1w,         // [B][H] ping-pong
               int* __restrict__ flags,        // NWG*FSTRIDE + go, pre-zeroed
               float* __restrict__ out,        // [B][T][H]
               float* __restrict__ hlast) {    // [B][H]
    __shared__ float Ua[JPW][HID + 4];
    __shared__ float Uz[JPW][HID + 4];
    __shared__ float red_a[3][128];
    __shared__ float red_z[3][128];

    int* go = flags + NWG * FSTRIDE;

    const int wg  = blockIdx.x;
    const int tid = threadIdx.x;
    const int j0  = wg * JPW;

    for (int f = tid; f < JPW * (HID / 4); f += 512) {
        int r = f / (HID / 4);
        int c = (f % (HID / 4)) * 4;
        *(float4*)&Ua[r][c] = *(const float4*)&U[(size_t)(j0 + r) * HID + c];
        *(float4*)&Uz[r][c] = *(const float4*)&U[(size_t)(HID + j0 + r) * HID + c];
    }
    __syncthreads();

    const int p  = tid & 127;
    const int q  = tid >> 7;        // K-quarter 0..3
    const int b  = p >> 2;          // 0..31
    const int jl = p & 3;           // 0..3
    const int jg = j0 + jl;
    const int k0 = q * 256;

    float* hcur = h0w;
    float* hnxt = h1w;

    for (int t = 0; t < TLEN; ++t) {
        // prefetch this step's w (plain cached loads; read-only input)
        float wa = 0.f, wz = 0.f;
        if (!q) {
            const float* wt = &w[((size_t)t * BATCH + b) * G2];
            wa = wt[jg];
            wz = wt[HID + jg];
        }

        const float* hb = hcur + (size_t)b * HID + k0;
        const float* ua = &Ua[jl][k0];
        const float* uz = &Uz[jl][k0];
        float sa0 = 0.f, sa1 = 0.f, sz0 = 0.f, sz1 = 0.f;
        #pragma unroll 8
        for (int k = 0; k < 256; k += 8) {
            uint64_t u0 = ld_h2(&hb[k]);
            uint64_t u1 = ld_h2(&hb[k + 2]);
            uint64_t u2 = ld_h2(&hb[k + 4]);
            uint64_t u3 = ld_h2(&hb[k + 6]);
            float4 av0 = *(const float4*)&ua[k];
            float4 av1 = *(const float4*)&ua[k + 4];
            float4 zv0 = *(const float4*)&uz[k];
            float4 zv1 = *(const float4*)&uz[k + 4];
            float h0f = lo_f(u0), h1f = hi_f(u0), h2f = lo_f(u1), h3f = hi_f(u1);
            float h4f = lo_f(u2), h5f = hi_f(u2), h6f = lo_f(u3), h7f = hi_f(u3);
            sa0 += h0f * av0.x + h1f * av0.y + h2f * av0.z + h3f * av0.w;
            sa1 += h4f * av1.x + h5f * av1.y + h6f * av1.z + h7f * av1.w;
            sz0 += h0f * zv0.x + h1f * zv0.y + h2f * zv0.z + h3f * zv0.w;
            sz1 += h4f * zv1.x + h5f * zv1.y + h6f * zv1.z + h7f * zv1.w;
        }
        float sa = sa0 + sa1;
        float sz = sz0 + sz1;

        if (q) { red_a[q - 1][p] = sa; red_z[q - 1][p] = sz; }
        __syncthreads();
        if (!q) {
            sa += red_a[0][p] + red_a[1][p] + red_a[2][p];
            sz += red_z[0][p] + red_z[1][p] + red_z[2][p];
            float at = wa + sa;
            float zt = wz + sz;
            zt = 1.f / (1.f + expf(-zt));
            float hc = tanhf(at);
            float hold = ld_h(&hcur[(size_t)b * HID + jg]);
            float hnew = zt * hold + (1.f - zt) * hc;
            out[((size_t)b * TLEN + t) * HID + jg] = hnew;        // plain store
            st_h(&hnxt[(size_t)b * HID + jg], hnew);              // coherent
            if (t == TLEN - 1) hlast[(size_t)b * HID + jg] = hnew;
        }

        if (t < TLEN - 1) {
            const int ep = t + 1;
            __syncthreads();   // drains vmcnt -> h stores at LLC
            if (wg == 0) {
                if (tid >= 1 && tid < NWG) {
                    while (ld_flag(&flags[tid * FSTRIDE]) < ep)
                        __builtin_amdgcn_s_sleep(1);
                }
                __syncthreads();                 // all arrivals observed
                if (tid == 0) st_flag(go, ep);
            } else {
                if (tid == 0) {
                    st_flag(&flags[wg * FSTRIDE], ep);
                    while (ld_flag(go) < ep)
                        __builtin_amdgcn_s_sleep(4);
                }
            }
            __syncthreads();
        }
        float* tmp = hcur; hcur = hnxt; hnxt = tmp;
    }
}

// ---------------------------------------------------------------------------
extern "C" void kernel_launch(void* const* d_in, const int* in_sizes, int n_in,
                              void* d_out, int out_size, void* d_ws, size_t ws_size,
                              hipStream_t stream) {
    (void)in_sizes; (void)n_in; (void)out_size; (void)ws_size;

    const float* x  = (const float*)d_in[0];
    const float* W0 = (const float*)d_in[1];
    const float* U0 = (const float*)d_in[2];
    const float* W1 = (const float*)d_in[3];
    const float* U1 = (const float*)d_in[4];

    float* out    = (float*)d_out;                              // [B,T,H]
    float* hstack = out + (size_t)BATCH * TLEN * HID;           // [2,B,H]

    int*   flags = (int*)d_ws;                                  // 256*16 + 16
    float* h0    = (float*)d_ws + NWG * FSTRIDE + 16;           // [B,H]
    float* h1    = h0 + BATCH * HID;                            // [B,H]
    float* wbuf  = h1 + BATCH * HID;                            // [T][B][2H]

    dim3 gg(16384 / 128, 2048 / 128);
    int init_blocks = (BATCH * HID + NWG * FSTRIDE + 16 + 255) / 256;

    // ---- layer 0 ----
    proj_gemm<<<gg, 256, 0, stream>>>(x, W0, wbuf, 512);
    rec_init<<<init_blocks, 256, 0, stream>>>(h0, flags);
    ligru_rec<<<dim3(NWG), dim3(512), 0, stream>>>(wbuf, U0, h0, h1, flags,
                                                   out, hstack);

    // ---- layer 1 ---- (reads layer-0 output staged in d_out, then overwrites)
    proj_gemm<<<gg, 256, 0, stream>>>(out, W1, wbuf, 1024);
    rec_init<<<init_blocks, 256, 0, stream>>>(h0, flags);
    ligru_rec<<<dim3(NWG), dim3(512), 0, stream>>>(wbuf, U1, h0, h1, flags,
                                                   out, hstack + BATCH * HID);
}

// Round 5
// 7862.418 us; speedup vs baseline: 3.5258x; 3.5258x over previous
//
#include <hip/hip_runtime.h>
#include <math.h>

#define BATCH 32
#define TLEN  512
#define HID   1024
#define G2    2048   // 2*H

// ---------------------------------------------------------------------------
// Projection GEMM: Cw[t][b][n] = sum_k A[m][k] * W[n][k],  m = b*TLEN + t
// Output permuted to [T][B][2H] so the recurrence reads contiguous slabs.
// ---------------------------------------------------------------------------
__global__ __launch_bounds__(256)
void proj_gemm(const float* __restrict__ A, const float* __restrict__ W,
               float* __restrict__ Cw, int K) {
    __shared__ float As[16][132];
    __shared__ float Bs[16][132];

    const int bm = blockIdx.x;
    const int bn = blockIdx.y;
    const int tid = threadIdx.x;
    const int tx = tid & 15;
    const int ty = tid >> 4;

    const int row0 = bm * 128;
    const int col0 = bn * 128;

    float acc[8][8];
    #pragma unroll
    for (int i = 0; i < 8; ++i)
        #pragma unroll
        for (int j = 0; j < 8; ++j) acc[i][j] = 0.f;

    for (int k0 = 0; k0 < K; k0 += 16) {
        #pragma unroll
        for (int i = 0; i < 2; ++i) {
            int f = tid + i * 256;
            int r = f >> 2;
            int c = (f & 3) * 4;
            float4 va = *(const float4*)&A[(size_t)(row0 + r) * K + k0 + c];
            As[c + 0][r] = va.x; As[c + 1][r] = va.y;
            As[c + 2][r] = va.z; As[c + 3][r] = va.w;
            float4 vb = *(const float4*)&W[(size_t)(col0 + r) * K + k0 + c];
            Bs[c + 0][r] = vb.x; Bs[c + 1][r] = vb.y;
            Bs[c + 2][r] = vb.z; Bs[c + 3][r] = vb.w;
        }
        __syncthreads();

        #pragma unroll
        for (int kk = 0; kk < 16; ++kk) {
            float a[8], b[8];
            #pragma unroll
            for (int i = 0; i < 8; ++i) a[i] = As[kk][ty * 8 + i];
            #pragma unroll
            for (int j = 0; j < 8; ++j) b[j] = Bs[kk][tx * 8 + j];
            #pragma unroll
            for (int i = 0; i < 8; ++i)
                #pragma unroll
                for (int j = 0; j < 8; ++j)
                    acc[i][j] += a[i] * b[j];
        }
        __syncthreads();
    }

    #pragma unroll
    for (int i = 0; i < 8; ++i) {
        int m = row0 + ty * 8 + i;
        int t = m & (TLEN - 1);
        int bb = m >> 9;
        float* dst = &Cw[((size_t)t * BATCH + bb) * G2 + col0 + tx * 8];
        #pragma unroll
        for (int j = 0; j < 8; ++j) dst[j] = acc[i][j];
    }
}

// ---------------------------------------------------------------------------
// Agent-scope (device-coherent) helpers: global_load/store sc0 sc1 (bypass
// L1/L2, hit LLC). No fences, no cache-maintenance ops.
// ---------------------------------------------------------------------------
__device__ __forceinline__ void st_flag(int* p, int v) {
    __hip_atomic_store(p, v, __ATOMIC_RELAXED, __HIP_MEMORY_SCOPE_AGENT);
}
__device__ __forceinline__ int ld_flag(const int* p) {
    return __hip_atomic_load(p, __ATOMIC_RELAXED, __HIP_MEMORY_SCOPE_AGENT);
}
__device__ __forceinline__ void st_h(float* p, float v) {
    __hip_atomic_store(p, v, __ATOMIC_RELAXED, __HIP_MEMORY_SCOPE_AGENT);
}
__device__ __forceinline__ uint64_t ld_h2(const float* p) {
    return __hip_atomic_load((const uint64_t*)p, __ATOMIC_RELAXED,
                             __HIP_MEMORY_SCOPE_AGENT);
}

#define NWG 256
#define FSTRIDE 16   // flags 64 B apart
#define BT 4         // batches per WG
#define JT 32        // j-outputs per WG
#define KS 8         // k-split (8 waves, wave = k-octant)

__global__ void rec_init(float* h0, int* flags) {
    int i = blockIdx.x * 256 + threadIdx.x;
    if (i < BATCH * HID) h0[i] = 0.f;
    if (i < NWG * FSTRIDE + 16) flags[i] = 0;
}

// ---------------------------------------------------------------------------
// Recurrence. Partition: WG = (bt 0..7, jb 0..31) owns batches [bt*4,bt*4+4)
// x gate outputs j in [jb*32, jb*32+32). U-slice (64 rows) lives in REGISTERS
// (float4 ureg[32] = 128 VGPR/thread, loaded once). Per step only 16 KB of h
// is staged into LDS (coherent loads). MAC-loop LDS reads are all-lane
// broadcasts (wave = single k-octant). Tree barrier from R4 (one spinner/WG).
// ---------------------------------------------------------------------------
__global__ __launch_bounds__(512, 1)
void ligru_rec(const float* __restrict__ w,    // [T][B][2H]
               const float* __restrict__ U,    // [2H][H]
               float* h0w, float* h1w,         // [B][H] ping-pong
               int* __restrict__ flags,        // NWG*FSTRIDE + go
               float* __restrict__ out,        // [B][T][H]
               float* __restrict__ hlast) {    // [B][H]
    __shared__ float hsh[BT * HID];            // 16 KB staged h
    __shared__ float red[KS][64][BT];          // 8 KB k-partials

    int* go = flags + NWG * FSTRIDE;

    const int wg  = blockIdx.x;
    const int tid = threadIdx.x;
    const int bt  = wg >> 5;          // 0..7
    const int jb  = wg & 31;          // 0..31
    const int j0  = jb * JT;
    const int bg0 = bt * BT;          // first global batch of this WG

    const int ks = tid >> 6;          // wave id = k-octant 0..7
    const int g  = tid & 63;          // lane = gate row (g<32: a_j, g>=32: z_j)
    const int urow = (g < 32) ? (j0 + g) : (HID + j0 + (g - 32));
    const int k0 = ks * 128;

    // ---- U slice -> registers (once; static indices so it stays in VGPRs)
    float4 ureg[32];
    {
        const float* up = &U[(size_t)urow * HID + k0];
        #pragma unroll
        for (int i = 0; i < 32; ++i)
            ureg[i] = *(const float4*)&up[i * 4];
    }

    float* hcur = h0w;
    float* hnxt = h1w;

    for (int t = 0; t < TLEN; ++t) {
        // ---- stage h[bg0..bg0+4][:] into LDS (16 KB, coherent, coalesced)
        {
            const float* src = hcur + (size_t)bg0 * HID;
            #pragma unroll
            for (int c = 0; c < 2; ++c) {
                int off = c * 2048 + tid * 4;
                uint64_t u0 = ld_h2(src + off);
                uint64_t u1 = ld_h2(src + off + 2);
                float4 v;
                ((uint64_t*)&v)[0] = u0;
                ((uint64_t*)&v)[1] = u1;
                *(float4*)&hsh[off] = v;    // stride-16B ds_write_b128, clean
            }
        }
        // ---- prefetch w for gate threads (plain cached loads)
        float wa = 0.f, wz = 0.f;
        if (tid < BT * JT) {              // 128 gate threads
            int bl = tid >> 5;
            int jl = tid & 31;
            const float* wt = &w[((size_t)t * BATCH + bg0 + bl) * G2];
            wa = wt[j0 + jl];
            wz = wt[HID + j0 + jl];
        }
        __syncthreads();

        // ---- MAC: 4 batches x 128 k per thread; LDS reads are broadcasts
        float a0 = 0.f, a1 = 0.f, a2 = 0.f, a3 = 0.f;
        {
            const float* hp = &hsh[k0];
            #pragma unroll
            for (int i = 0; i < 32; ++i) {
                float4 uv  = ureg[i];
                float4 h0v = *(const float4*)&hp[0 * HID + i * 4];
                float4 h1v = *(const float4*)&hp[1 * HID + i * 4];
                float4 h2v = *(const float4*)&hp[2 * HID + i * 4];
                float4 h3v = *(const float4*)&hp[3 * HID + i * 4];
                a0 += uv.x * h0v.x + uv.y * h0v.y + uv.z * h0v.z + uv.w * h0v.w;
                a1 += uv.x * h1v.x + uv.y * h1v.y + uv.z * h1v.z + uv.w * h1v.w;
                a2 += uv.x * h2v.x + uv.y * h2v.y + uv.z * h2v.z + uv.w * h2v.w;
                a3 += uv.x * h3v.x + uv.y * h3v.y + uv.z * h3v.z + uv.w * h3v.w;
            }
        }
        *(float4*)&red[ks][g][0] = make_float4(a0, a1, a2, a3);
        __syncthreads();

        // ---- gates + state update (128 threads)
        if (tid < BT * JT) {
            int bl = tid >> 5;
            int jl = tid & 31;
            float sa = 0.f, sz = 0.f;
            #pragma unroll
            for (int k = 0; k < KS; ++k) {
                sa += red[k][jl][bl];
                sz += red[k][32 + jl][bl];
            }
            float at = wa + sa;
            float zt = wz + sz;
            zt = 1.f / (1.f + expf(-zt));
            float hc = tanhf(at);
            float hold = hsh[bl * HID + j0 + jl];        // h[t-1] from LDS
            float hnew = zt * hold + (1.f - zt) * hc;
            int bg = bg0 + bl;
            out[((size_t)bg * TLEN + t) * HID + j0 + jl] = hnew;   // plain
            st_h(&hnxt[(size_t)bg * HID + j0 + jl], hnew);         // coherent
            if (t == TLEN - 1) hlast[(size_t)bg * HID + j0 + jl] = hnew;
        }

        // ---- grid barrier (two-hop tree, one spinner per WG)
        if (t < TLEN - 1) {
            const int ep = t + 1;
            __syncthreads();   // drains vmcnt -> h stores at LLC
            if (wg == 0) {
                if (tid >= 1 && tid < NWG) {
                    while (ld_flag(&flags[tid * FSTRIDE]) < ep)
                        __builtin_amdgcn_s_sleep(1);
                }
                __syncthreads();
                if (tid == 0) st_flag(go, ep);
            } else {
                if (tid == 0) {
                    st_flag(&flags[wg * FSTRIDE], ep);
                    while (ld_flag(go) < ep)
                        __builtin_amdgcn_s_sleep(4);
                }
            }
            __syncthreads();
        }
        float* tmp = hcur; hcur = hnxt; hnxt = tmp;
    }
}

// ---------------------------------------------------------------------------
extern "C" void kernel_launch(void* const* d_in, const int* in_sizes, int n_in,
                              void* d_out, int out_size, void* d_ws, size_t ws_size,
                              hipStream_t stream) {
    (void)in_sizes; (void)n_in; (void)out_size; (void)ws_size;

    const float* x  = (const float*)d_in[0];
    const float* W0 = (const float*)d_in[1];
    const float* U0 = (const float*)d_in[2];
    const float* W1 = (const float*)d_in[3];
    const float* U1 = (const float*)d_in[4];

    float* out    = (float*)d_out;                              // [B,T,H]
    float* hstack = out + (size_t)BATCH * TLEN * HID;           // [2,B,H]

    int*   flags = (int*)d_ws;                                  // 256*16 + 16
    float* h0    = (float*)d_ws + NWG * FSTRIDE + 16;           // [B,H]
    float* h1    = h0 + BATCH * HID;                            // [B,H]
    float* wbuf  = h1 + BATCH * HID;                            // [T][B][2H]

    dim3 gg(16384 / 128, 2048 / 128);
    int init_blocks = (BATCH * HID + NWG * FSTRIDE + 16 + 255) / 256;

    // ---- layer 0 ----
    proj_gemm<<<gg, 256, 0, stream>>>(x, W0, wbuf, 512);
    rec_init<<<init_blocks, 256, 0, stream>>>(h0, flags);
    ligru_rec<<<dim3(NWG), dim3(512), 0, stream>>>(wbuf, U0, h0, h1, flags,
                                                   out, hstack);

    // ---- layer 1 ---- (reads layer-0 output staged in d_out, then overwrites)
    proj_gemm<<<gg, 256, 0, stream>>>(out, W1, wbuf, 1024);
    rec_init<<<init_blocks, 256, 0, stream>>>(h0, flags);
    ligru_rec<<<dim3(NWG), dim3(512), 0, stream>>>(wbuf, U1, h0, h1, flags,
                                                   out, hstack + BATCH * HID);
}

// Round 6
// 6884.765 us; speedup vs baseline: 4.0264x; 1.1420x over previous
//
#include <hip/hip_runtime.h>
#include <math.h>

#define BATCH 32
#define TLEN  512
#define HID   1024
#define G2    2048   // 2*H

// ---------------------------------------------------------------------------
// Projection GEMM: Cw[t][b][n] = sum_k A[m][k] * W[n][k],  m = b*TLEN + t
// Output permuted to [T][B][2H] so the recurrence reads contiguous slabs.
// ---------------------------------------------------------------------------
__global__ __launch_bounds__(256)
void proj_gemm(const float* __restrict__ A, const float* __restrict__ W,
               float* __restrict__ Cw, int K) {
    __shared__ float As[16][132];
    __shared__ float Bs[16][132];

    const int bm = blockIdx.x;
    const int bn = blockIdx.y;
    const int tid = threadIdx.x;
    const int tx = tid & 15;
    const int ty = tid >> 4;

    const int row0 = bm * 128;
    const int col0 = bn * 128;

    float acc[8][8];
    #pragma unroll
    for (int i = 0; i < 8; ++i)
        #pragma unroll
        for (int j = 0; j < 8; ++j) acc[i][j] = 0.f;

    for (int k0 = 0; k0 < K; k0 += 16) {
        #pragma unroll
        for (int i = 0; i < 2; ++i) {
            int f = tid + i * 256;
            int r = f >> 2;
            int c = (f & 3) * 4;
            float4 va = *(const float4*)&A[(size_t)(row0 + r) * K + k0 + c];
            As[c + 0][r] = va.x; As[c + 1][r] = va.y;
            As[c + 2][r] = va.z; As[c + 3][r] = va.w;
            float4 vb = *(const float4*)&W[(size_t)(col0 + r) * K + k0 + c];
            Bs[c + 0][r] = vb.x; Bs[c + 1][r] = vb.y;
            Bs[c + 2][r] = vb.z; Bs[c + 3][r] = vb.w;
        }
        __syncthreads();

        #pragma unroll
        for (int kk = 0; kk < 16; ++kk) {
            float a[8], b[8];
            #pragma unroll
            for (int i = 0; i < 8; ++i) a[i] = As[kk][ty * 8 + i];
            #pragma unroll
            for (int j = 0; j < 8; ++j) b[j] = Bs[kk][tx * 8 + j];
            #pragma unroll
            for (int i = 0; i < 8; ++i)
                #pragma unroll
                for (int j = 0; j < 8; ++j)
                    acc[i][j] += a[i] * b[j];
        }
        __syncthreads();
    }

    #pragma unroll
    for (int i = 0; i < 8; ++i) {
        int m = row0 + ty * 8 + i;
        int t = m & (TLEN - 1);
        int bb = m >> 9;
        float* dst = &Cw[((size_t)t * BATCH + bb) * G2 + col0 + tx * 8];
        #pragma unroll
        for (int j = 0; j < 8; ++j) dst[j] = acc[i][j];
    }
}

// ---------------------------------------------------------------------------
// Agent-scope (device-coherent) helpers: global_load/store sc0 sc1 (bypass
// L1/L2, hit LLC). No fences, no cache-maintenance ops.
// ---------------------------------------------------------------------------
__device__ __forceinline__ void st_flag(int* p, int v) {
    __hip_atomic_store(p, v, __ATOMIC_RELAXED, __HIP_MEMORY_SCOPE_AGENT);
}
__device__ __forceinline__ int ld_flag(const int* p) {
    return __hip_atomic_load(p, __ATOMIC_RELAXED, __HIP_MEMORY_SCOPE_AGENT);
}
__device__ __forceinline__ void st_h(float* p, float v) {
    __hip_atomic_store(p, v, __ATOMIC_RELAXED, __HIP_MEMORY_SCOPE_AGENT);
}
__device__ __forceinline__ uint64_t ld_h2(const float* p) {
    return __hip_atomic_load((const uint64_t*)p, __ATOMIC_RELAXED,
                             __HIP_MEMORY_SCOPE_AGENT);
}

#define NWG 256
#define FSTRIDE 16   // flags 64 B apart
#define BT 4         // batches per WG
#define JT 32        // j-outputs per WG
#define KS 8         // k-split (8 waves, wave = k-octant)
#define BHID (BATCH * HID)

__global__ void rec_init(float* h0, int* flags) {
    int i = blockIdx.x * 256 + threadIdx.x;
    if (i < BHID) h0[i] = 0.f;
    if (i < NWG * FSTRIDE) flags[i] = 0;
}

// ---------------------------------------------------------------------------
// Recurrence with GROUP-LOCAL sync. WG wg: bt = wg&7 (batch group / XCD via
// round-robin dispatch), jb = wg>>3 (j-block). WG owns batches [bt*4,bt*4+4)
// x gates [jb*32, jb*32+32). Its h-slice is read ONLY by the 32 WGs with the
// same bt, and those are also the only WAR party -> sync within the 32-WG
// group, 8 groups run independently.
//
// h lives in a 3-deep ring (hbuf[3][B][H]); flag=t+1 posted after writing
// h(t+1). Before staging h(t), poll all 32 group flags >= t; this also
// implies peers staged h(t-2), so writing h(t+1) over h(t-2) is WAR-safe --
// no second barrier hop needed. Wave 0 polls (one flag per lane, one load
// instruction per round trip -- no spin storm). U-slice in registers.
// ---------------------------------------------------------------------------
__global__ __launch_bounds__(512, 1)
void ligru_rec(const float* __restrict__ w,    // [T][B][2H]
               const float* __restrict__ U,    // [2H][H]
               float* __restrict__ hbuf,       // [3][B][H] ring
               int* __restrict__ flags,        // NWG*FSTRIDE, pre-zeroed
               float* __restrict__ out,        // [B][T][H]
               float* __restrict__ hlast) {    // [B][H]
    __shared__ float hsh[BT * HID];            // 16 KB staged h
    __shared__ float red[KS][64][BT];          // 8 KB k-partials

    const int wg  = blockIdx.x;
    const int tid = threadIdx.x;
    const int bt  = wg & 7;           // group id (maps to XCD round-robin)
    const int jb  = wg >> 3;          // 0..31
    const int j0  = jb * JT;
    const int bg0 = bt * BT;          // first global batch of this WG

    const int ks = tid >> 6;          // wave id = k-octant 0..7
    const int g  = tid & 63;          // lane = gate row (g<32: a_j, g>=32: z_j)
    const int urow = (g < 32) ? (j0 + g) : (HID + j0 + (g - 32));
    const int k0 = ks * 128;

    // ---- U slice -> registers (once; static indices keep it in VGPRs)
    float4 ureg[32];
    {
        const float* up = &U[(size_t)urow * HID + k0];
        #pragma unroll
        for (int i = 0; i < 32; ++i)
            ureg[i] = *(const float4*)&up[i * 4];
    }

    float* h_t  = hbuf;               // h(t)   buffer
    float* h_n  = hbuf + BHID;        // h(t+1) buffer
    float* h_p  = hbuf + 2 * BHID;    // h(t+2) buffer (rotates)

    for (int t = 0; t < TLEN; ++t) {
        // ---- prefetch w (independent of h; HBM latency hides under poll)
        float wa = 0.f, wz = 0.f;
        if (tid < BT * JT) {
            int bl = tid >> 5;
            int jl = tid & 31;
            const float* wt = &w[((size_t)t * BATCH + bg0 + bl) * G2];
            wa = wt[j0 + jl];
            wz = wt[HID + j0 + jl];
        }

        // ---- wait for group peers to have published h(t)
        if (t > 0) {
            if (tid < 32) {
                const int* fp = &flags[(bt + (tid << 3)) * FSTRIDE];
                while (ld_flag(fp) < t)
                    __builtin_amdgcn_s_sleep(1);
            }
            __syncthreads();
        }

        // ---- stage h(t)[bg0..bg0+4][:] into LDS (16 KB, coherent)
        {
            const float* src = h_t + (size_t)bg0 * HID;
            #pragma unroll
            for (int c = 0; c < 2; ++c) {
                int off = c * 2048 + tid * 4;
                uint64_t u0 = ld_h2(src + off);
                uint64_t u1 = ld_h2(src + off + 2);
                float4 v;
                ((uint64_t*)&v)[0] = u0;
                ((uint64_t*)&v)[1] = u1;
                *(float4*)&hsh[off] = v;
            }
        }
        __syncthreads();

        // ---- MAC: 4 batches x 128 k per thread; LDS reads are broadcasts
        float a0 = 0.f, a1 = 0.f, a2 = 0.f, a3 = 0.f;
        {
            const float* hp = &hsh[k0];
            #pragma unroll
            for (int i = 0; i < 32; ++i) {
                float4 uv  = ureg[i];
                float4 h0v = *(const float4*)&hp[0 * HID + i * 4];
                float4 h1v = *(const float4*)&hp[1 * HID + i * 4];
                float4 h2v = *(const float4*)&hp[2 * HID + i * 4];
                float4 h3v = *(const float4*)&hp[3 * HID + i * 4];
                a0 += uv.x * h0v.x + uv.y * h0v.y + uv.z * h0v.z + uv.w * h0v.w;
                a1 += uv.x * h1v.x + uv.y * h1v.y + uv.z * h1v.z + uv.w * h1v.w;
                a2 += uv.x * h2v.x + uv.y * h2v.y + uv.z * h2v.z + uv.w * h2v.w;
                a3 += uv.x * h3v.x + uv.y * h3v.y + uv.z * h3v.z + uv.w * h3v.w;
            }
        }
        *(float4*)&red[ks][g][0] = make_float4(a0, a1, a2, a3);
        __syncthreads();

        // ---- gates + state update (128 threads)
        if (tid < BT * JT) {
            int bl = tid >> 5;
            int jl = tid & 31;
            float sa = 0.f, sz = 0.f;
            #pragma unroll
            for (int k = 0; k < KS; ++k) {
                sa += red[k][jl][bl];
                sz += red[k][32 + jl][bl];
            }
            float at = wa + sa;
            float zt = wz + sz;
            zt = 1.f / (1.f + expf(-zt));
            float hc = tanhf(at);
            float hold = hsh[bl * HID + j0 + jl];
            float hnew = zt * hold + (1.f - zt) * hc;
            int bg = bg0 + bl;
            out[((size_t)bg * TLEN + t) * HID + j0 + jl] = hnew;     // plain
            if (t < TLEN - 1) {
                st_h(&h_n[(size_t)bg * HID + j0 + jl], hnew);        // coherent
            } else {
                hlast[(size_t)bg * HID + j0 + jl] = hnew;
            }
        }

        // ---- publish: one store, no second hop (3-deep ring makes WAR free)
        if (t < TLEN - 1) {
            __syncthreads();   // drains vmcnt -> h stores at LLC
            if (tid == 0) st_flag(&flags[wg * FSTRIDE], t + 1);
        }

        float* tmp = h_t; h_t = h_n; h_n = h_p; h_p = tmp;   // rotate ring
    }
}

// ---------------------------------------------------------------------------
extern "C" void kernel_launch(void* const* d_in, const int* in_sizes, int n_in,
                              void* d_out, int out_size, void* d_ws, size_t ws_size,
                              hipStream_t stream) {
    (void)in_sizes; (void)n_in; (void)out_size; (void)ws_size;

    const float* x  = (const float*)d_in[0];
    const float* W0 = (const float*)d_in[1];
    const float* U0 = (const float*)d_in[2];
    const float* W1 = (const float*)d_in[3];
    const float* U1 = (const float*)d_in[4];

    float* out    = (float*)d_out;                              // [B,T,H]
    float* hstack = out + (size_t)BATCH * TLEN * HID;           // [2,B,H]

    int*   flags = (int*)d_ws;                                  // 256*16 ints
    float* hbuf  = (float*)d_ws + NWG * FSTRIDE;                // [3][B][H]
    float* wbuf  = hbuf + 3 * BHID;                             // [T][B][2H]

    dim3 gg(16384 / 128, 2048 / 128);
    int init_blocks = (BHID + 255) / 256;

    // ---- layer 0 ----
    proj_gemm<<<gg, 256, 0, stream>>>(x, W0, wbuf, 512);
    rec_init<<<init_blocks, 256, 0, stream>>>(hbuf, flags);
    ligru_rec<<<dim3(NWG), dim3(512), 0, stream>>>(wbuf, U0, hbuf, flags,
                                                   out, hstack);

    // ---- layer 1 ---- (reads layer-0 output staged in d_out, then overwrites)
    proj_gemm<<<gg, 256, 0, stream>>>(out, W1, wbuf, 1024);
    rec_init<<<init_blocks, 256, 0, stream>>>(hbuf, flags);
    ligru_rec<<<dim3(NWG), dim3(512), 0, stream>>>(wbuf, U1, hbuf, flags,
                                                   out, hstack + BATCH * HID);
}